// Round 1
// baseline (87.892 us; speedup 1.0000x reference)
//
#include <hip/hip_runtime.h>
#include <hip/hip_bf16.h>

// IDW interpolation, POWER=2.0: w = 1/d2 (sqrt cancels), out = sum(w*v)/sum(w).
// B=2, P=131072, S=512. One thread per (b,p); inner loop over S stations.
// Station data is wave-uniform -> compiler scalarizes to s_load (scalar cache),
// keeping VALU free for the 7-plain-op + 1-rcp inner body (~22 cyc/station/wave).

#define BLOCK 256

__global__ __launch_bounds__(BLOCK) void idw_kernel(
    const float* __restrict__ station_coords,  // (B, S, 2)
    const float* __restrict__ station_values,  // (B, S)
    const float* __restrict__ grid_points,     // (B, P, 2)
    float* __restrict__ out,                   // (B, P)
    int P, int S) {

    const int b = blockIdx.y;
    const int p = blockIdx.x * BLOCK + threadIdx.x;
    if (p >= P) return;

    const float2* __restrict__ sc2 = (const float2*)(station_coords) + (size_t)b * S;
    const float*  __restrict__ svb = station_values + (size_t)b * S;

    const float2 g = ((const float2*)grid_points)[(size_t)b * P + p];
    const float gx = g.x, gy = g.y;

    // EPS = float32 machine eps; reference: dist==0 -> EPS -> w = 1/EPS^2.
    constexpr float EPS  = 1.1920928955078125e-07f;
    constexpr float EPS2 = EPS * EPS;

    float wsum = 0.0f;
    float vsum = 0.0f;

#pragma unroll 8
    for (int s = 0; s < S; ++s) {
        const float2 sxy = sc2[s];       // wave-uniform -> s_load_dwordx2
        const float  v   = svb[s];       // wave-uniform -> s_load_dword
        const float dx = gx - sxy.x;
        const float dy = gy - sxy.y;
        float d2 = fmaf(dx, dx, dy * dy);
        d2 = fmaxf(d2, EPS2);            // exact dist==0 semantics, safe otherwise
        const float w = __builtin_amdgcn_rcpf(d2);
        wsum += w;
        vsum = fmaf(w, v, vsum);
    }

    out[(size_t)b * P + p] = vsum / wsum;  // once per thread: precise div is fine
}

extern "C" void kernel_launch(void* const* d_in, const int* in_sizes, int n_in,
                              void* d_out, int out_size, void* d_ws, size_t ws_size,
                              hipStream_t stream) {
    const float* station_coords = (const float*)d_in[0];
    const float* station_values = (const float*)d_in[1];
    const float* grid_points    = (const float*)d_in[2];
    float* out = (float*)d_out;

    const int B = 2;
    const int S = in_sizes[1] / B;   // 512
    const int P = out_size / B;      // 131072

    dim3 grid((P + BLOCK - 1) / BLOCK, B);
    dim3 block(BLOCK);
    idw_kernel<<<grid, block, 0, stream>>>(station_coords, station_values,
                                           grid_points, out, P, S);
}